// Round 5
// baseline (216.787 us; speedup 1.0000x reference)
//
#include <hip/hip_runtime.h>
#include <stdint.h>

typedef __attribute__((ext_vector_type(8))) short bf16x8;
typedef __attribute__((ext_vector_type(4))) short bf16x4;
typedef __attribute__((ext_vector_type(4))) float f32x4;

#define NSPLIT 4
#define WAVES 4
#define STAGES 8                       // per wave: 8 stages x 16 rows = 128 rows
#define STAGE_FLOATS (16 * 64)         // 1024 floats = 4 KB per stage
#define A_STRIDE 40                    // shorts; 80 B rows (16B aligned)
#define VB_STRIDE 68                   // padded fp32 row stride for reduction

static __device__ __forceinline__ unsigned short f2bf(float f) {
    union { float f; unsigned int i; } x; x.f = f;
    unsigned int i = x.i;
    return (unsigned short)((i + 0x7FFFu + ((i >> 16) & 1u)) >> 16);  // RNE
}

static __device__ __forceinline__ bf16x8 cvt8(float4 a, float4 b) {
    bf16x8 r;
    r[0] = (short)f2bf(a.x); r[1] = (short)f2bf(a.y);
    r[2] = (short)f2bf(a.z); r[3] = (short)f2bf(a.w);
    r[4] = (short)f2bf(b.x); r[5] = (short)f2bf(b.y);
    r[6] = (short)f2bf(b.z); r[7] = (short)f2bf(b.w);
    return r;
}

// VALU-pipe 16-lane sum via DPP row rotations (row_ror:8,4,2,1)
static __device__ __forceinline__ float row_sum16(float x) {
    union fi { float f; int i; };
    fi a, b; a.f = x;
    b.i = __builtin_amdgcn_mov_dpp(a.i, 0x128, 0xf, 0xf, false); a.f += b.f;
    b.i = __builtin_amdgcn_mov_dpp(a.i, 0x124, 0xf, 0xf, false); a.f += b.f;
    b.i = __builtin_amdgcn_mov_dpp(a.i, 0x122, 0xf, 0xf, false); a.f += b.f;
    b.i = __builtin_amdgcn_mov_dpp(a.i, 0x121, 0xf, 0xf, false); a.f += b.f;
    return a.f;
}

// async global->LDS DMA, 16 B/lane, lds dest = uniform base + lane*16 (m97/m104)
static __device__ __forceinline__ void dma16(const float* g, float* l) {
    __builtin_amdgcn_global_load_lds(
        (const __attribute__((address_space(1))) void*)g,
        (__attribute__((address_space(3))) void*)l, 16, 0, 0);
}

// Grid: 1024 blocks = 256 m x 4 n-quarters. Block: 256 thr = 4 waves.
// Per wave: 128 rows as 8 stages of 16. R staged fp32 via global_load_lds
// (unsinkable -> HBM stream stays deep); GEMM1 A-frags from global (L2-warm).
// Partial v accumulated per block, combined with atomicAdd into pre-zeroed out.
__global__ __launch_bounds__(256, 3)
void netvlad_fused(const float* __restrict__ R,
                   const float* __restrict__ W,
                   const float* __restrict__ bias,
                   const float* __restrict__ cent,
                   float* __restrict__ out)
{
    __shared__ float dma[WAVES][2][STAGE_FLOATS];      // 32 KB (dbuf DMA tiles)
    __shared__ short a_lds_s[WAVES][32 * A_STRIDE];    // 10 KB
    __shared__ float suma_buf[2][32];

    const int tid  = threadIdx.x;
    const int wave = tid >> 6;
    const int lane = tid & 63;
    const int l15  = lane & 15;
    const int quad = lane >> 4;
    const int m    = blockIdx.x >> 2;
    const int q    = blockIdx.x & 3;

    const float* Rm  = R + (size_t)m * (2048 * 64);
    const int row0   = q * 512 + wave * 128;

    short* a_lds = a_lds_s[wave];
    float* buf0  = dma[wave][0];
    float* buf1  = dma[wave][1];

    // W fragments (GEMM1 B-operand): lane reads W row (kt*16+l15), cols cc*32+quad*8
    bf16x8 wf[2][2];
#pragma unroll
    for (int kt = 0; kt < 2; ++kt)
#pragma unroll
        for (int cc = 0; cc < 2; ++cc) {
            const float* wp = W + (kt*16 + l15)*64 + cc*32 + quad*8;
            wf[kt][cc] = cvt8(*(const float4*)wp, *(const float4*)(wp + 4));
        }
    float bval[2];
    bval[0] = bias[l15];
    bval[1] = bias[16 + l15];

    f32x4 acc[2][4];
#pragma unroll
    for (int kt = 0; kt < 2; ++kt)
#pragma unroll
        for (int ct = 0; ct < 4; ++ct)
            acc[kt][ct] = (f32x4){0.f, 0.f, 0.f, 0.f};
    float suma[2] = {0.f, 0.f};

    // prologue: DMA stage0 -> buf0, then af(0) direct loads (order matters:
    // af(0)'s compiler-inserted vmcnt wait implies DMA(0) landed — in-order vmcnt)
    {
        const float* src = Rm + (size_t)row0 * 64;
#pragma unroll
        for (int t = 0; t < 4; ++t)
            dma16(src + t*256 + lane*4, buf0 + t*256);
    }
    float4 cur[4];
    {
        const float* p = Rm + (size_t)row0*64 + l15*64 + quad*8;
        cur[0] = *(const float4*)p;        cur[1] = *(const float4*)(p + 4);
        cur[2] = *(const float4*)(p + 32); cur[3] = *(const float4*)(p + 36);
    }

#pragma unroll
    for (int s = 0; s < STAGES; ++s) {
        float* bufn = (s & 1) ? buf0 : buf1;
        const float* nsrc = Rm + (size_t)(row0 + (s+1)*16) * 64;

        // even stages: DMA next stage at top (odd stages issue after GEMM2 — WAR)
        if (!(s & 1) && s + 1 < STAGES) {
#pragma unroll
            for (int t = 0; t < 4; ++t)
                dma16(nsrc + t*256 + lane*4, bufn + t*256);
        }
        // depth-1 register prefetch of next stage's A-frag data (L2/MSHR-warm)
        float4 nxt[4];
        if (s + 1 < STAGES) {
            const float* p = nsrc + l15*64 + quad*8;
            nxt[0] = *(const float4*)p;        nxt[1] = *(const float4*)(p + 4);
            nxt[2] = *(const float4*)(p + 32); nxt[3] = *(const float4*)(p + 36);
        }

        // GEMM1: 16 rows x 32 k (4 MFMAs)
        bf16x8 af0 = cvt8(cur[0], cur[1]);
        bf16x8 af1 = cvt8(cur[2], cur[3]);
        f32x4 d1[2];
#pragma unroll
        for (int kt = 0; kt < 2; ++kt) {
            f32x4 d = (f32x4){0.f, 0.f, 0.f, 0.f};
            d = __builtin_amdgcn_mfma_f32_16x16x32_bf16(af0, wf[kt][0], d, 0, 0, 0);
            d = __builtin_amdgcn_mfma_f32_16x16x32_bf16(af1, wf[kt][1], d, 0, 0, 0);
            d1[kt] = d;
        }

        // softmax over k; row = quad*4 + r (16 rows), k = kt*16 + l15
        bf16x4 p0, p1;
        float a0s = 0.f, a1s = 0.f;
#pragma unroll
        for (int r = 0; r < 4; ++r) {
            float l0 = d1[0][r] + bval[0];
            float l1 = d1[1][r] + bval[1];
            float e0 = __expf(l0);
            float e1 = __expf(l1);
            float ss = row_sum16(e0 + e1);
            float rs = __builtin_amdgcn_rcpf(ss);
            float a0 = e0 * rs, a1 = e1 * rs;
            a0s += a0; a1s += a1;
            p0[r] = (short)f2bf(a0);
            p1[r] = (short)f2bf(a1);
        }
        suma[0] += a0s; suma[1] += a1s;
        // a_lds[k][n32]: n32 = (s&1)*16 + quad*4 .. +3
        *(bf16x4*)(a_lds + l15*A_STRIDE        + (s&1)*16 + quad*4) = p0;
        *(bf16x4*)(a_lds + (16 + l15)*A_STRIDE + (s&1)*16 + quad*4) = p1;

        if (s & 1) {   // GEMM2 over the 32-row window (stages s-1, s)
            // reorder barrier; correctness already implied by af-waits + in-order vmcnt
            asm volatile("s_waitcnt vmcnt(4)" ::: "memory");

            bf16x8 a2[2];
            a2[0] = *(bf16x8*)(a_lds + l15*A_STRIDE        + quad*8);
            a2[1] = *(bf16x8*)(a_lds + (16 + l15)*A_STRIDE + quad*8);

            // B-gather: n = quad*8+j; n<16 in buf0 (even stage), n>=16 in buf1
            const float* bb = (quad < 2) ? buf0 : buf1;
            const float* bp = bb + (quad & 1) * 8 * 64 + l15;
#pragma unroll
            for (int ct = 0; ct < 4; ++ct) {
                const float* bq = bp + ct*16;
                bf16x8 b2;
#pragma unroll
                for (int j = 0; j < 8; ++j)
                    b2[j] = (short)f2bf(bq[j*64]);
                acc[0][ct] = __builtin_amdgcn_mfma_f32_16x16x32_bf16(a2[0], b2, acc[0][ct], 0, 0, 0);
                acc[1][ct] = __builtin_amdgcn_mfma_f32_16x16x32_bf16(a2[1], b2, acc[1][ct], 0, 0, 0);
            }
            // now safe to overwrite the even buffer (its ds_reads retired)
            if (s + 1 < STAGES) {
#pragma unroll
                for (int t = 0; t < 4; ++t)
                    dma16(nsrc + t*256 + lane*4, bufn + t*256);
            }
        }

        if (s + 1 < STAGES) {
            cur[0] = nxt[0]; cur[1] = nxt[1]; cur[2] = nxt[2]; cur[3] = nxt[3];
        }
    }

    // fold suma over quads (k = l15 / 16+l15 per lane)
#pragma unroll
    for (int kt = 0; kt < 2; ++kt) {
        suma[kt] += __shfl_xor(suma[kt], 16);
        suma[kt] += __shfl_xor(suma[kt], 32);
    }

    // cross-wave tree reduction (4 waves: steps 2,1), aliasing dma as fp32 buf
    float* vbuf = (float*)dma;
    __syncthreads();
    if (wave >= 2) {
        float* dst = vbuf + (wave - 2) * (32 * VB_STRIDE);
#pragma unroll
        for (int kt = 0; kt < 2; ++kt)
#pragma unroll
            for (int ct = 0; ct < 4; ++ct)
#pragma unroll
                for (int r = 0; r < 4; ++r)
                    dst[(kt*16 + quad*4 + r)*VB_STRIDE + ct*16 + l15] = acc[kt][ct][r];
        if (lane < 16) {
            suma_buf[wave - 2][lane]      = suma[0];
            suma_buf[wave - 2][lane + 16] = suma[1];
        }
    }
    __syncthreads();
    if (wave < 2) {
        const float* src = vbuf + wave * (32 * VB_STRIDE);
#pragma unroll
        for (int kt = 0; kt < 2; ++kt)
#pragma unroll
            for (int ct = 0; ct < 4; ++ct)
#pragma unroll
                for (int r = 0; r < 4; ++r)
                    acc[kt][ct][r] += src[(kt*16 + quad*4 + r)*VB_STRIDE + ct*16 + l15];
        suma[0] += suma_buf[wave][l15];
        suma[1] += suma_buf[wave][l15 + 16];
    }
    __syncthreads();
    if (wave == 1) {
#pragma unroll
        for (int kt = 0; kt < 2; ++kt)
#pragma unroll
            for (int ct = 0; ct < 4; ++ct)
#pragma unroll
                for (int r = 0; r < 4; ++r)
                    vbuf[(kt*16 + quad*4 + r)*VB_STRIDE + ct*16 + l15] = acc[kt][ct][r];
        if (lane < 16) {
            suma_buf[0][lane]      = suma[0];
            suma_buf[0][lane + 16] = suma[1];
        }
    }
    __syncthreads();
    if (wave == 0) {
#pragma unroll
        for (int kt = 0; kt < 2; ++kt)
#pragma unroll
            for (int ct = 0; ct < 4; ++ct)
#pragma unroll
                for (int r = 0; r < 4; ++r)
                    acc[kt][ct][r] += vbuf[(kt*16 + quad*4 + r)*VB_STRIDE + ct*16 + l15];
        suma[0] += suma_buf[0][l15];
        suma[1] += suma_buf[0][l15 + 16];

        // atomic epilogue: out += v_partial - suma_partial * cent
        float* op = out + (size_t)m * (32*64);
#pragma unroll
        for (int kt = 0; kt < 2; ++kt) {
#pragma unroll
            for (int r = 0; r < 4; ++r) {
                const int k = kt*16 + quad*4 + r;
                const float su = __shfl(suma[kt], quad*4 + r);
#pragma unroll
                for (int ct = 0; ct < 4; ++ct) {
                    const int c = ct*16 + l15;
                    atomicAdd(&op[k*64 + c], acc[kt][ct][r] - su * cent[k*64 + c]);
                }
            }
        }
    }
}

extern "C" void kernel_launch(void* const* d_in, const int* in_sizes, int n_in,
                              void* d_out, int out_size, void* d_ws, size_t ws_size,
                              hipStream_t stream) {
    (void)in_sizes; (void)n_in; (void)out_size; (void)d_ws; (void)ws_size;
    const float* R = (const float*)d_in[0];   // R_seq (8,32,2048,64) fp32
    const float* W = (const float*)d_in[1];   // W (32,64) fp32
    const float* b = (const float*)d_in[2];   // b (32,) fp32
    const float* c = (const float*)d_in[3];   // centroids (32,64) fp32
    float* out = (float*)d_out;               // (8,32,32,64) fp32

    hipMemsetAsync(out, 0, (size_t)256 * 32 * 64 * sizeof(float), stream);
    hipLaunchKernelGGL(netvlad_fused, dim3(256 * NSPLIT), dim3(256), 0, stream,
                       R, W, b, c, out);
}